// Round 13
// baseline (2260.586 us; speedup 1.0000x reference)
//
#include <hip/hip_runtime.h>
#include <cmath>

// Leaky RNN:  h_t = 0.9 h_{t-1} + 0.1 tanh(h W_hh + u_t W_uh + b_h);  y_t = h_t W_hy + b_y
// B=64, T=2048, N_in=128, N_h=512, N_out=128.
//
// Phase 2 (critical path): one WG per batch row, 1024 threads = 16 waves.
// Round-12 post-mortem: the allocator targets 2 blocks/CU for 1024-thread blocks
// (VGPR cap 64), so the 16 "register-resident" W quads (64 regs) were rematerialized
// from L2 every step (VGPR_Count=44).  Our grid is 64 blocks on 256 CUs — a second
// co-resident block never exists.  Fix: pad static LDS to 90.6 KB (>160/2) so two
// blocks CANNOT co-reside -> allocator must budget 1 block/CU = 128 VGPR/thread;
// demand ~100 fits.  W_hh then truly register-resident: no LDS W, no L2 W stream.
// Wave (kc=w&7, ch=w>>3); lane l owns cols ch*256+4l+0..3, k in [64kc,64kc+64).
// v_dot4_i32_i8, exact int32 accumulation, per-column scales; h int8 (S_H) in LDS;
// f32 recurrence state; partials int32 [8][512] (conflict-free).  2 barriers/step.
//
// ws: U (f16 [B*T][512], 128 MiB) | H (f16 [B*T][512], 128 MiB).
// Wpk (256 KiB int8 W) + scale bufs live in d_out (dead until y_gemm runs last).

#define NB 64
#define NT 2048
#define NI 128
#define NH 512
#define NO 128
#define S_H 4.6f

typedef unsigned short u16;
typedef unsigned int u32;
typedef _Float16 half2_t __attribute__((ext_vector_type(2)));

__device__ __forceinline__ int sdot4(u32 a, u32 b, int c) {
#if __has_builtin(__builtin_amdgcn_sdot4)
    return __builtin_amdgcn_sdot4(a, b, c, false);
#else
    int r = c;
    r += (int)(signed char)(a) * (int)(signed char)(b);
    r += (int)(signed char)(a >> 8) * (int)(signed char)(b >> 8);
    r += (int)(signed char)(a >> 16) * (int)(signed char)(b >> 16);
    r += (int)(signed char)(a >> 24) * (int)(signed char)(b >> 24);
    return r;
#endif
}

__device__ __forceinline__ u16 ftoh(float x) { return __builtin_bit_cast(u16, (_Float16)x); }
__device__ __forceinline__ float htof(u16 x) { return (float)__builtin_bit_cast(_Float16, x); }

// ---------------- Phase -1: per-column |max| of W_hh -> scales ----------------
__global__ __launch_bounds__(256) void wscale(const float* __restrict__ Whh,
                                              float* __restrict__ sbuf,
                                              float* __restrict__ cbuf) {
    const int n0 = blockIdx.x * 64;
    const int r = threadIdx.x >> 6, c = threadIdx.x & 63;
    const int n = n0 + c;
    float m = 0.f;
    for (int k = r; k < NH; k += 4) m = fmaxf(m, fabsf(Whh[(size_t)k * NH + n]));
    __shared__ float red[4][64];
    red[r][c] = m;
    __syncthreads();
    if (r == 0) {
        m = fmaxf(fmaxf(red[0][c], red[1][c]), fmaxf(red[2][c], red[3][c]));
        m = fmaxf(m, 1e-8f);
        sbuf[n] = m * (1.f / 127.f);
        cbuf[n] = S_H * m * (1.f / 16129.f);
    }
}

// ---------------- Phase 0: pack W_hh to int8, consumer order ----------------
// idx = sec*8192 + (((ch*8+kc)*4+q)*2+ci)*64 + l.  sec 0: cols ch*256+4l+ci;
// sec 1: cols ch*256+4l+2+ci.  kb = kc*64 + q*16; uint4 = 16 int8, word j = k kb+4j..+3.
__global__ __launch_bounds__(256) void wpack(const float* __restrict__ Whh,
                                             const float* __restrict__ sbuf,
                                             uint4* __restrict__ Wpk) {
    const int idx = blockIdx.x * 256 + threadIdx.x;   // 0..16383
    const int sec = idx >> 13;
    const int r = idx & 8191;
    const int l = r & 63;
    const int ci = (r >> 6) & 1;
    const int q = (r >> 7) & 3;
    const int kc = (r >> 9) & 7;
    const int ch = r >> 12;
    const int col = ch * 256 + 4 * l + (sec ? 2 : 0) + ci;
    const int kb = kc * 64 + q * 16;
    const float inv = 1.f / sbuf[col];
    u32 words[4];
    #pragma unroll
    for (int wd = 0; wd < 4; ++wd) {
        u32 acc = 0;
        #pragma unroll
        for (int j = 0; j < 4; ++j) {
            const int k = kb + wd * 4 + j;
            float qv = rintf(Whh[(size_t)k * NH + col] * inv);
            qv = fminf(fmaxf(qv, -127.f), 127.f);
            acc |= ((u32)((int)qv & 0xFF)) << (8 * j);
        }
        words[wd] = acc;
    }
    uint4 o; o.x = words[0]; o.y = words[1]; o.z = words[2]; o.w = words[3];
    Wpk[idx] = o;
}

// ---------------- Phase 1: U[m][n] = u[m][:] @ W_uh[:,n] + b_h[n]  (f16 out) ----------------
__global__ __launch_bounds__(256) void u_gemm(
        const float* __restrict__ A,    // u  [M][NI]
        const float* __restrict__ Bw,   // W_uh [NI][NH]
        const float* __restrict__ bh,   // [NH]
        u16* __restrict__ C) {          // U [M][NH] f16
    const int n0 = blockIdx.x * 64;
    const int m0 = blockIdx.y * 64;
    const int tid = threadIdx.x;
    const int tn = tid & 15, tm = tid >> 4;
    __shared__ float As[64][68];   // [k][m]
    __shared__ float Bs[64][68];   // [k][n]
    float acc[4][4] = {};
    for (int k0 = 0; k0 < NI; k0 += 64) {
        const int r = tid >> 4, c4 = tid & 15;
        #pragma unroll
        for (int p = 0; p < 4; ++p) {
            const int row = r + p * 16;
            float4 v = *reinterpret_cast<const float4*>(&A[(size_t)(m0 + row) * NI + k0 + c4 * 4]);
            As[c4 * 4 + 0][row] = v.x; As[c4 * 4 + 1][row] = v.y;
            As[c4 * 4 + 2][row] = v.z; As[c4 * 4 + 3][row] = v.w;
        }
        #pragma unroll
        for (int p = 0; p < 4; ++p) {
            const int row = r + p * 16;
            float4 v = *reinterpret_cast<const float4*>(&Bw[(size_t)(k0 + row) * NH + n0 + c4 * 4]);
            *reinterpret_cast<float4*>(&Bs[row][c4 * 4]) = v;
        }
        __syncthreads();
        #pragma unroll
        for (int kk = 0; kk < 64; ++kk) {
            float4 av = *reinterpret_cast<const float4*>(&As[kk][tm * 4]);
            float4 bv = *reinterpret_cast<const float4*>(&Bs[kk][tn * 4]);
            const float am[4] = {av.x, av.y, av.z, av.w};
            const float bn[4] = {bv.x, bv.y, bv.z, bv.w};
            #pragma unroll
            for (int i = 0; i < 4; ++i)
                #pragma unroll
                for (int j = 0; j < 4; ++j)
                    acc[i][j] += am[i] * bn[j];
        }
        __syncthreads();
    }
    float bias[4];
    #pragma unroll
    for (int j = 0; j < 4; ++j) bias[j] = bh[n0 + tn * 4 + j];
    #pragma unroll
    for (int i = 0; i < 4; ++i) {
        const int m = m0 + tm * 4 + i;
        ushort4 out;
        out.x = ftoh(acc[i][0] + bias[0]);
        out.y = ftoh(acc[i][1] + bias[1]);
        out.z = ftoh(acc[i][2] + bias[2]);
        out.w = ftoh(acc[i][3] + bias[3]);
        *reinterpret_cast<ushort4*>(&C[(size_t)m * NH + n0 + tn * 4]) = out;
    }
}

// ---------------- Phase 2: sequential recurrence (int8 dot4, W in registers) ----------------
#define DOT16(HG, WQ, ACC)                 \
    ACC = sdot4((HG).x, (WQ).x, ACC);      \
    ACC = sdot4((HG).y, (WQ).y, ACC);      \
    ACC = sdot4((HG).z, (WQ).z, ACC);      \
    ACC = sdot4((HG).w, (WQ).w, ACC);

__global__ __attribute__((amdgpu_flat_work_group_size(1024, 1024), amdgpu_waves_per_eu(4, 4)))
void rnn_seq(const float* __restrict__ h0,    // [NB][NH]
             const u16* __restrict__ U,       // [NB*NT][NH] f16
             u16* __restrict__ H,             // [NB*NT][NH] f16 (out)
             const uint4* __restrict__ Wpk,   // int8 W, 16384 uint4 (sec0:8192, sec1:8192)
             const float* __restrict__ cbuf) {// per-col pre-scales [NH]
    const int b = blockIdx.x;
    const int tid = threadIdx.x;
    const int w = tid >> 6, l = tid & 63;
    const int kc = w & 7, ch = w >> 3;

    __shared__ __align__(16) int part2[8][NH];      // int32 partials, 16 KiB
    __shared__ __align__(16) u32 h8[NH / 4];        // int8 h, 512 B
    // Occupancy fence: static LDS > 80 KiB forces 1 block/CU, which makes the register
    // allocator budget 128 VGPR/thread (16 waves = 4/SIMD) instead of the 64-VGPR
    // 2-blocks/CU target that rematerialized our W registers in rounds 11-12.
    __shared__ u32 lds_fence[18432];                // 72 KiB, kept live below

    u16* __restrict__ Hrow = H + (size_t)b * NT * NH + tid;

    // Data-dependent guard the compiler cannot fold: keeps lds_fence allocated.
    if (cbuf[NH - 1] > 1e30f) {
        lds_fence[tid] = tid;
        __syncthreads();
        Hrow[0] = (u16)lds_fence[1023 - tid];
    }

    // W_hh fully register-resident: 16 named uint4 (cols ch*256+4l+0..3 x k-quads 0..3).
    const uint4* __restrict__ w0b = Wpk + (size_t)(ch * 8 + kc) * 512 + l;         // cols 0,1
    const uint4* __restrict__ w1b = Wpk + 8192 + (size_t)(ch * 8 + kc) * 512 + l;  // cols 2,3
    uint4 s0_0 = w0b[0],   s0_1 = w0b[64],  s0_2 = w1b[0],   s0_3 = w1b[64];   // q0
    uint4 s1_0 = w0b[128], s1_1 = w0b[192], s1_2 = w1b[128], s1_3 = w1b[192];  // q1
    uint4 s2_0 = w0b[256], s2_1 = w0b[320], s2_2 = w1b[256], s2_3 = w1b[320];  // q2
    uint4 s3_0 = w0b[384], s3_1 = w0b[448], s3_2 = w1b[384], s3_3 = w1b[448];  // q3

    float hreg = 0.f, cf_reg = 0.f;
    if (tid < NH) {
        hreg = h0[b * NH + tid];
        cf_reg = cbuf[tid];
        float qv = rintf(hreg * (127.f / S_H));
        qv = fminf(fmaxf(qv, -127.f), 127.f);
        reinterpret_cast<unsigned char*>(h8)[tid] = (unsigned char)((int)qv);
    }
    __syncthreads();

    const u16* __restrict__ Urow = U + (size_t)b * NT * NH + tid;
    const uint4* __restrict__ hqb = reinterpret_cast<const uint4*>(h8) + kc * 4;

    u16 ub_cur = (tid < NH) ? Urow[0] : (u16)0;

    #pragma unroll 1
    for (int t = 0; t < NT; ++t) {
        u16 ub_nxt = 0;
        if (tid < NH) ub_nxt = Urow[(size_t)(t + 1) * NH];   // safe: H follows U in ws

        uint4 hA = hqb[0], hB = hqb[1];
        int acc0 = 0, acc1 = 0, acc2 = 0, acc3 = 0;

        // q0
        DOT16(hA, s0_0, acc0) DOT16(hA, s0_1, acc1) DOT16(hA, s0_2, acc2) DOT16(hA, s0_3, acc3)
        hA = hqb[2];
        // q1
        DOT16(hB, s1_0, acc0) DOT16(hB, s1_1, acc1) DOT16(hB, s1_2, acc2) DOT16(hB, s1_3, acc3)
        hB = hqb[3];
        // q2
        DOT16(hA, s2_0, acc0) DOT16(hA, s2_1, acc1) DOT16(hA, s2_2, acc2) DOT16(hA, s2_3, acc3)
        // q3
        DOT16(hB, s3_0, acc0) DOT16(hB, s3_1, acc1) DOT16(hB, s3_2, acc2) DOT16(hB, s3_3, acc3)

        // Partials: cols ch*256+4l+0..3 -> one int4 store (dense, conflict-free).
        int4 pw; pw.x = acc0; pw.y = acc1; pw.z = acc2; pw.w = acc3;
        *reinterpret_cast<int4*>(&part2[kc][ch * 256 + 4 * l]) = pw;
        __syncthreads();

        // Update h[tid]: exact int32 8-way k-chunk reduction (lanes consecutive, free).
        if (tid < NH) {
            const int isum = ((part2[0][tid] + part2[1][tid]) + (part2[2][tid] + part2[3][tid]))
                           + ((part2[4][tid] + part2[5][tid]) + (part2[6][tid] + part2[7][tid]));
            const float pre = (float)isum * cf_reg + htof(ub_cur);
            const float e = __expf(2.f * pre);
            hreg = 0.9f * hreg + 0.1f * (1.f - 2.f / (e + 1.f));
            Hrow[(size_t)t * NH] = ftoh(hreg);
            float qv = rintf(hreg * (127.f / S_H));
            qv = fminf(fmaxf(qv, -127.f), 127.f);
            reinterpret_cast<unsigned char*>(h8)[tid] = (unsigned char)((int)qv);
        }
        ub_cur = ub_nxt;
        __syncthreads();
    }
}

// ---------------- Phase 3: Y[m][n] = H[m][:] @ W_hy[:,n] + b_y[n]  (fp32 out) ----------------
__global__ __launch_bounds__(256) void y_gemm(
        const u16* __restrict__ H,      // [M][NH] f16
        const float* __restrict__ Why,  // [NH][NO]
        const float* __restrict__ by,   // [NO]
        float* __restrict__ Y) {        // [M][NO]
    const int m0 = blockIdx.x * 64;
    const int tid = threadIdx.x;
    const int tn = tid & 15, tm = tid >> 4;
    __shared__ float As[64][68];    // [k][m]
    __shared__ float Bs[64][132];   // [k][n]
    float acc[4][8] = {};
    for (int k0 = 0; k0 < NH; k0 += 64) {
        #pragma unroll
        for (int p = 0; p < 4; ++p) {
            const int idx = tid + p * 256;
            const int r = idx >> 4;
            const int c4 = idx & 15;
            ushort4 v = *reinterpret_cast<const ushort4*>(&H[(size_t)(m0 + r) * NH + k0 + c4 * 4]);
            As[c4 * 4 + 0][r] = htof(v.x); As[c4 * 4 + 1][r] = htof(v.y);
            As[c4 * 4 + 2][r] = htof(v.z); As[c4 * 4 + 3][r] = htof(v.w);
        }
        #pragma unroll
        for (int p = 0; p < 8; ++p) {
            const int idx = tid + p * 256;
            const int r = idx >> 5;
            const int c4 = idx & 31;
            float4 v = *reinterpret_cast<const float4*>(&Why[(size_t)(k0 + r) * NO + c4 * 4]);
            *reinterpret_cast<float4*>(&Bs[r][c4 * 4]) = v;
        }
        __syncthreads();
        #pragma unroll
        for (int kk = 0; kk < 64; ++kk) {
            float4 av = *reinterpret_cast<const float4*>(&As[kk][tm * 4]);
            float4 b0 = *reinterpret_cast<const float4*>(&Bs[kk][tn * 8]);
            float4 b1 = *reinterpret_cast<const float4*>(&Bs[kk][tn * 8 + 4]);
            const float am[4] = {av.x, av.y, av.z, av.w};
            const float bn[8] = {b0.x, b0.y, b0.z, b0.w, b1.x, b1.y, b1.z, b1.w};
            #pragma unroll
            for (int i = 0; i < 4; ++i)
                #pragma unroll
                for (int j = 0; j < 8; ++j)
                    acc[i][j] += am[i] * bn[j];
        }
        __syncthreads();
    }
    float bias[8];
    #pragma unroll
    for (int j = 0; j < 8; ++j) bias[j] = by[tn * 8 + j];
    #pragma unroll
    for (int i = 0; i < 4; ++i) {
        const int m = m0 + tm * 4 + i;
        float4 o0, o1;
        o0.x = acc[i][0] + bias[0]; o0.y = acc[i][1] + bias[1];
        o0.z = acc[i][2] + bias[2]; o0.w = acc[i][3] + bias[3];
        o1.x = acc[i][4] + bias[4]; o1.y = acc[i][5] + bias[5];
        o1.z = acc[i][6] + bias[6]; o1.w = acc[i][7] + bias[7];
        *reinterpret_cast<float4*>(&Y[(size_t)m * NO + tn * 8]) = o0;
        *reinterpret_cast<float4*>(&Y[(size_t)m * NO + tn * 8 + 4]) = o1;
    }
}

extern "C" void kernel_launch(void* const* d_in, const int* in_sizes, int n_in,
                              void* d_out, int out_size, void* d_ws, size_t ws_size,
                              hipStream_t stream) {
    const float* u   = (const float*)d_in[0];   // [64][2048][128]
    const float* h0  = (const float*)d_in[1];   // [64][512]
    const float* Wuh = (const float*)d_in[2];   // [128][512]
    const float* Whh = (const float*)d_in[3];   // [512][512]
    const float* Why = (const float*)d_in[4];   // [512][128]
    const float* bh  = (const float*)d_in[5];   // [512]
    const float* by  = (const float*)d_in[6];   // [128]
    float* y = (float*)d_out;                   // [64][2048][128] fp32

    u16* Uws = (u16*)d_ws;                       // 128 MiB
    u16* Hws = Uws + (size_t)NB * NT * NH;       // 128 MiB
    // Scratch in d_out (dead until y_gemm overwrites all of it last):
    uint4* Wpk  = (uint4*)d_out;                 // 256 KiB int8 W
    float* sbuf = (float*)(Wpk + 16384);         // 2 KiB quant steps
    float* cbuf = sbuf + NH;                     // 2 KiB pre-scales
    (void)in_sizes; (void)n_in; (void)out_size; (void)ws_size;

    wscale<<<dim3(8), 256, 0, stream>>>(Whh, sbuf, cbuf);
    wpack<<<dim3(64), 256, 0, stream>>>(Whh, sbuf, Wpk);
    u_gemm<<<dim3(NH / 64, (NB * NT) / 64), 256, 0, stream>>>(u, Wuh, bh, Uws);
    rnn_seq<<<dim3(NB), 1024, 0, stream>>>(h0, Uws, Hws, Wpk, cbuf);
    y_gemm<<<dim3((NB * NT) / 64), 256, 0, stream>>>(Hws, Why, by, y);
}